// Round 2
// baseline (1275.367 us; speedup 1.0000x reference)
//
#include <hip/hip_runtime.h>
#include <hip/hip_bf16.h>

#define N_NODES 100000
#define N_EDGES 800000
#define HD 256
#define NG 128

// ---------- order-preserving float <-> uint map (for atomicMax pooling) ----------
__device__ __forceinline__ unsigned f2key(float f){
  unsigned u = __float_as_uint(f);
  return (u & 0x80000000u) ? ~u : (u | 0x80000000u);
}
__device__ __forceinline__ float key2f(unsigned k){
  unsigned u = (k & 0x80000000u) ? (k & 0x7FFFFFFFu) : ~k;
  return __uint_as_float(u);
}

// ---------- CSR build ----------
__global__ void k_deg(const int* __restrict__ ei, int* __restrict__ deg){
  int e = blockIdx.x*256 + threadIdx.x;
  const int M = N_EDGES + N_NODES;
  if(e < M){
    int c = (e < N_EDGES) ? ei[N_EDGES + e] : (e - N_EDGES);
    atomicAdd(&deg[c], 1);
  }
}

__global__ void k_scan1(const int* __restrict__ deg, int* __restrict__ ptr,
                        int* __restrict__ partials){
  __shared__ int s[256];
  int tid = threadIdx.x;
  int i = blockIdx.x*256 + tid;
  int v = (i < N_NODES) ? deg[i] : 0;
  s[tid] = v; __syncthreads();
  for(int off=1; off<256; off<<=1){
    int t = (tid >= off) ? s[tid-off] : 0;
    __syncthreads();
    s[tid] += t;
    __syncthreads();
  }
  if(i < N_NODES) ptr[i] = s[tid] - v;     // exclusive within chunk
  if(tid == 255) partials[blockIdx.x] = s[255];
}

__global__ void k_scan2(int* __restrict__ partials, int nb, int* __restrict__ ptrN){
  if(threadIdx.x == 0 && blockIdx.x == 0){
    int run = 0;
    for(int b=0;b<nb;b++){ int t = partials[b]; partials[b] = run; run += t; }
    *ptrN = run;
  }
}

__global__ void k_scan3(int* __restrict__ ptr, const int* __restrict__ partials,
                        int* __restrict__ cursor){
  int i = blockIdx.x*256 + threadIdx.x;
  if(i < N_NODES){
    int v = ptr[i] + partials[blockIdx.x];
    ptr[i] = v; cursor[i] = v;
  }
}

__global__ void k_fill(const int* __restrict__ ei, int* __restrict__ cursor,
                       int* __restrict__ src){
  int e = blockIdx.x*256 + threadIdx.x;
  const int M = N_EDGES + N_NODES;
  if(e < M){
    int r, c;
    if(e < N_EDGES){ r = ei[e]; c = ei[N_EDGES + e]; }
    else           { r = c = e - N_EDGES; }
    int pos = atomicAdd(&cursor[c], 1);
    src[pos] = r;
  }
}

__global__ void k_dinv(const int* __restrict__ deg, float* __restrict__ dinv){
  int i = blockIdx.x*256 + threadIdx.x;
  if(i < N_NODES) dinv[i] = rsqrtf((float)deg[i]);   // deg >= 1 (self-loops)
}

// ---------- f32 GEMM: out[N,256] = A[N,256] @ W[256,256] (no bias) ----------
__global__ __launch_bounds__(256) void k_gemm(const float* __restrict__ A,
                                              const float* __restrict__ W,
                                              float* __restrict__ out){
  __shared__ float As[16][132];   // [k][m], padded
  __shared__ float Bs[16][132];   // [k][n], padded
  int tid = threadIdx.x;
  int ty = tid >> 4, tx = tid & 15;
  float acc[8][8];
  #pragma unroll
  for(int i=0;i<8;i++)
    #pragma unroll
    for(int j=0;j<8;j++) acc[i][j] = 0.f;

  int ar = tid >> 1;            // 0..127
  int ac = (tid & 1) << 3;      // 0 or 8
  int grow = blockIdx.x*128 + ar;
  int brow = tid >> 4;          // 0..15
  int bcol = (tid & 15) << 3;   // 0..120
  const float* aptr = A + (size_t)grow*HD + ac;
  const float* bptr = W + (size_t)brow*HD + blockIdx.y*128 + bcol;
  bool aval = grow < N_NODES;

  for(int k0=0;k0<HD;k0+=16){
    float4 a0 = make_float4(0,0,0,0), a1 = a0;
    if(aval){ a0 = *(const float4*)(aptr); a1 = *(const float4*)(aptr+4); }
    float4 b0 = *(const float4*)(bptr);
    float4 b1 = *(const float4*)(bptr+4);
    aptr += 16; bptr += (size_t)16*HD;
    __syncthreads();
    As[ac+0][ar]=a0.x; As[ac+1][ar]=a0.y; As[ac+2][ar]=a0.z; As[ac+3][ar]=a0.w;
    As[ac+4][ar]=a1.x; As[ac+5][ar]=a1.y; As[ac+6][ar]=a1.z; As[ac+7][ar]=a1.w;
    *(float4*)&Bs[brow][bcol]   = b0;
    *(float4*)&Bs[brow][bcol+4] = b1;
    __syncthreads();
    #pragma unroll
    for(int kk=0;kk<16;kk++){
      float a[8], b[8];
      *(float4*)&a[0] = *(const float4*)&As[kk][ty*8];
      *(float4*)&a[4] = *(const float4*)&As[kk][ty*8+4];
      *(float4*)&b[0] = *(const float4*)&Bs[kk][tx*8];
      *(float4*)&b[4] = *(const float4*)&Bs[kk][tx*8+4];
      #pragma unroll
      for(int i=0;i<8;i++)
        #pragma unroll
        for(int j=0;j<8;j++) acc[i][j] = fmaf(a[i], b[j], acc[i][j]);
    }
  }
  int rowBase = blockIdx.x*128 + ty*8;
  int colBase = blockIdx.y*128 + tx*8;
  #pragma unroll
  for(int i=0;i<8;i++){
    int r = rowBase + i;
    if(r < N_NODES){
      float4 v0 = make_float4(acc[i][0],acc[i][1],acc[i][2],acc[i][3]);
      float4 v1 = make_float4(acc[i][4],acc[i][5],acc[i][6],acc[i][7]);
      *(float4*)(out + (size_t)r*HD + colBase)     = v0;
      *(float4*)(out + (size_t)r*HD + colBase + 4) = v1;
    }
  }
}

// ---------- aggregation: out[v] = dinv[v] * sum_{r in in(v)} dinv[r]*t[r] + bias ----------
// one wave per node; lane handles 4 features (float4)
template<int RELU, int POOL>
__global__ __launch_bounds__(256) void k_agg(const float* __restrict__ t,
    const int* __restrict__ ptr, const int* __restrict__ src,
    const float* __restrict__ dinv, const float* __restrict__ bias,
    float* __restrict__ out, unsigned* __restrict__ gkeys,
    const int* __restrict__ batch){
  int v = blockIdx.x*4 + (threadIdx.x >> 6);
  if(v >= N_NODES) return;
  int f = (threadIdx.x & 63) * 4;
  float4 acc = make_float4(0,0,0,0);
  int j0 = ptr[v], j1 = ptr[v+1];
  for(int j=j0;j<j1;j++){
    int r = src[j];
    float w = dinv[r];
    float4 hv = *(const float4*)(t + (size_t)r*HD + f);
    acc.x = fmaf(w, hv.x, acc.x);
    acc.y = fmaf(w, hv.y, acc.y);
    acc.z = fmaf(w, hv.z, acc.z);
    acc.w = fmaf(w, hv.w, acc.w);
  }
  float dv = dinv[v];
  float4 b4 = *(const float4*)(bias + f);
  acc.x = fmaf(acc.x, dv, b4.x);
  acc.y = fmaf(acc.y, dv, b4.y);
  acc.z = fmaf(acc.z, dv, b4.z);
  acc.w = fmaf(acc.w, dv, b4.w);
  if(RELU){
    acc.x = fmaxf(acc.x, 0.f); acc.y = fmaxf(acc.y, 0.f);
    acc.z = fmaxf(acc.z, 0.f); acc.w = fmaxf(acc.w, 0.f);
  }
  if(POOL){
    int g = batch[v];
    unsigned* gp = gkeys + (size_t)g*HD + f;
    atomicMax(gp+0, f2key(acc.x));
    atomicMax(gp+1, f2key(acc.y));
    atomicMax(gp+2, f2key(acc.z));
    atomicMax(gp+3, f2key(acc.w));
  } else {
    *(float4*)(out + (size_t)v*HD + f) = acc;
  }
}

// ---------- head: logits = g @ Wc + bc; log_softmax ----------
__global__ void k_head(const unsigned* __restrict__ gk, const float* __restrict__ Wc,
                       const float* __restrict__ bc, float* __restrict__ out){
  int i = threadIdx.x;
  if(i >= NG) return;
  float a0 = 0.f, a1 = 0.f;
  for(int k=0;k<HD;k++){
    float gv = key2f(gk[(size_t)i*HD + k]);
    a0 = fmaf(gv, Wc[2*k],   a0);
    a1 = fmaf(gv, Wc[2*k+1], a1);
  }
  a0 += bc[0]; a1 += bc[1];
  float m = fmaxf(a0, a1);
  float lse = m + logf(expf(a0-m) + expf(a1-m));
  out[2*i]   = a0 - lse;
  out[2*i+1] = a1 - lse;
}

extern "C" void kernel_launch(void* const* d_in, const int* in_sizes, int n_in,
                              void* d_out, int out_size, void* d_ws, size_t ws_size,
                              hipStream_t stream){
  (void)in_sizes; (void)n_in; (void)out_size; (void)ws_size;
  const float* x   = (const float*)d_in[0];
  const int*   ei  = (const int*)d_in[1];
  const int*   bat = (const int*)d_in[2];
  const float* W1  = (const float*)d_in[3];
  const float* b1  = (const float*)d_in[4];
  const float* W2  = (const float*)d_in[5];
  const float* b2  = (const float*)d_in[6];
  const float* Wc  = (const float*)d_in[7];
  const float* bc  = (const float*)d_in[8];
  float* out = (float*)d_out;

  char* ws = (char*)d_ws;
  size_t off = 0;
  auto alloc = [&](size_t bytes)->void*{
    void* p = ws + off; off = (off + bytes + 255) & ~(size_t)255; return p;
  };
  float*    T      = (float*)alloc((size_t)N_NODES*HD*4);
  float*    Hb     = (float*)alloc((size_t)N_NODES*HD*4);
  int*      deg    = (int*)alloc((size_t)N_NODES*4);
  float*    dinv   = (float*)alloc((size_t)N_NODES*4);
  int*      ptr    = (int*)alloc((size_t)(N_NODES+1)*4);
  int*      cursor = (int*)alloc((size_t)N_NODES*4);
  int*      src    = (int*)alloc((size_t)(N_EDGES+N_NODES)*4);
  int*      partials = (int*)alloc(512*4);
  unsigned* gkeys  = (unsigned*)alloc((size_t)NG*HD*4);

  const int M = N_EDGES + N_NODES;
  const int nbM = (M + 255)/256;
  const int nbN = (N_NODES + 255)/256;

  hipMemsetAsync(deg,   0, (size_t)N_NODES*4, stream);
  hipMemsetAsync(gkeys, 0, (size_t)NG*HD*4,   stream);

  k_deg  <<<nbM, 256, 0, stream>>>(ei, deg);
  k_scan1<<<nbN, 256, 0, stream>>>(deg, ptr, partials);
  k_scan2<<<1,   64,  0, stream>>>(partials, nbN, ptr + N_NODES);
  k_scan3<<<nbN, 256, 0, stream>>>(ptr, partials, cursor);
  k_fill <<<nbM, 256, 0, stream>>>(ei, cursor, src);
  k_dinv <<<nbN, 256, 0, stream>>>(deg, dinv);

  dim3 ggrid((N_NODES + 127)/128, HD/128);
  k_gemm<<<ggrid, 256, 0, stream>>>(x, W1, T);
  k_agg<1,0><<<(N_NODES+3)/4, 256, 0, stream>>>(T, ptr, src, dinv, b1, Hb, nullptr, nullptr);
  k_gemm<<<ggrid, 256, 0, stream>>>(Hb, W2, T);
  k_agg<0,1><<<(N_NODES+3)/4, 256, 0, stream>>>(T, ptr, src, dinv, b2, nullptr, gkeys, bat);
  k_head<<<1, 128, 0, stream>>>(gkeys, Wc, bc, out);
}

// Round 3
// 1266.865 us; speedup vs baseline: 1.0067x; 1.0067x over previous
//
#include <hip/hip_runtime.h>
#include <hip/hip_bf16.h>

#define N_NODES 100000
#define N_EDGES 800000
#define HD 256
#define NG 128

// ---------- order-preserving float <-> uint map (for atomicMax pooling) ----------
__device__ __forceinline__ unsigned f2key(float f){
  unsigned u = __float_as_uint(f);
  return (u & 0x80000000u) ? ~u : (u | 0x80000000u);
}
__device__ __forceinline__ float key2f(unsigned k){
  unsigned u = (k & 0x80000000u) ? (k & 0x7FFFFFFFu) : ~k;
  return __uint_as_float(u);
}

// ---------- CSR build ----------
__global__ void k_deg(const int* __restrict__ ei, int* __restrict__ deg){
  int e = blockIdx.x*256 + threadIdx.x;
  const int M = N_EDGES + N_NODES;
  if(e < M){
    int c = (e < N_EDGES) ? ei[N_EDGES + e] : (e - N_EDGES);
    atomicAdd(&deg[c], 1);
  }
}

__global__ void k_scan1(const int* __restrict__ deg, int* __restrict__ ptr,
                        int* __restrict__ partials){
  __shared__ int s[256];
  int tid = threadIdx.x;
  int i = blockIdx.x*256 + tid;
  int v = (i < N_NODES) ? deg[i] : 0;
  s[tid] = v; __syncthreads();
  for(int off=1; off<256; off<<=1){
    int t = (tid >= off) ? s[tid-off] : 0;
    __syncthreads();
    s[tid] += t;
    __syncthreads();
  }
  if(i < N_NODES) ptr[i] = s[tid] - v;     // exclusive within chunk
  if(tid == 255) partials[blockIdx.x] = s[255];
}

__global__ void k_scan2(int* __restrict__ partials, int nb, int* __restrict__ ptrN){
  if(threadIdx.x == 0 && blockIdx.x == 0){
    int run = 0;
    for(int b=0;b<nb;b++){ int t = partials[b]; partials[b] = run; run += t; }
    *ptrN = run;
  }
}

__global__ void k_scan3(int* __restrict__ ptr, const int* __restrict__ partials,
                        int* __restrict__ cursor){
  int i = blockIdx.x*256 + threadIdx.x;
  if(i < N_NODES){
    int v = ptr[i] + partials[blockIdx.x];
    ptr[i] = v; cursor[i] = v;
  }
}

__global__ void k_fill(const int* __restrict__ ei, int* __restrict__ cursor,
                       int* __restrict__ src){
  int e = blockIdx.x*256 + threadIdx.x;
  const int M = N_EDGES + N_NODES;
  if(e < M){
    int r, c;
    if(e < N_EDGES){ r = ei[e]; c = ei[N_EDGES + e]; }
    else           { r = c = e - N_EDGES; }
    int pos = atomicAdd(&cursor[c], 1);
    src[pos] = r;
  }
}

__global__ void k_dinv(const int* __restrict__ deg, float* __restrict__ dinv){
  int i = blockIdx.x*256 + threadIdx.x;
  if(i < N_NODES) dinv[i] = rsqrtf((float)deg[i]);   // deg >= 1 (self-loops)
}

// ---------- f32 GEMM: out[N,256] = (A[N,256] @ W[256,256]) * scale[row] ----------
__global__ __launch_bounds__(256) void k_gemm(const float* __restrict__ A,
                                              const float* __restrict__ W,
                                              const float* __restrict__ scale,
                                              float* __restrict__ out){
  __shared__ float As[16][132];   // [k][m], padded
  __shared__ float Bs[16][132];   // [k][n], padded
  int tid = threadIdx.x;
  int ty = tid >> 4, tx = tid & 15;
  float acc[8][8];
  #pragma unroll
  for(int i=0;i<8;i++)
    #pragma unroll
    for(int j=0;j<8;j++) acc[i][j] = 0.f;

  int ar = tid >> 1;            // 0..127
  int ac = (tid & 1) << 3;      // 0 or 8
  int grow = blockIdx.x*128 + ar;
  int brow = tid >> 4;          // 0..15
  int bcol = (tid & 15) << 3;   // 0..120
  const float* aptr = A + (size_t)grow*HD + ac;
  const float* bptr = W + (size_t)brow*HD + blockIdx.y*128 + bcol;
  bool aval = grow < N_NODES;

  for(int k0=0;k0<HD;k0+=16){
    float4 a0 = make_float4(0,0,0,0), a1 = a0;
    if(aval){ a0 = *(const float4*)(aptr); a1 = *(const float4*)(aptr+4); }
    float4 b0 = *(const float4*)(bptr);
    float4 b1 = *(const float4*)(bptr+4);
    aptr += 16; bptr += (size_t)16*HD;
    __syncthreads();
    As[ac+0][ar]=a0.x; As[ac+1][ar]=a0.y; As[ac+2][ar]=a0.z; As[ac+3][ar]=a0.w;
    As[ac+4][ar]=a1.x; As[ac+5][ar]=a1.y; As[ac+6][ar]=a1.z; As[ac+7][ar]=a1.w;
    *(float4*)&Bs[brow][bcol]   = b0;
    *(float4*)&Bs[brow][bcol+4] = b1;
    __syncthreads();
    #pragma unroll
    for(int kk=0;kk<16;kk++){
      float a[8], b[8];
      *(float4*)&a[0] = *(const float4*)&As[kk][ty*8];
      *(float4*)&a[4] = *(const float4*)&As[kk][ty*8+4];
      *(float4*)&b[0] = *(const float4*)&Bs[kk][tx*8];
      *(float4*)&b[4] = *(const float4*)&Bs[kk][tx*8+4];
      #pragma unroll
      for(int i=0;i<8;i++)
        #pragma unroll
        for(int j=0;j<8;j++) acc[i][j] = fmaf(a[i], b[j], acc[i][j]);
    }
  }
  int rowBase = blockIdx.x*128 + ty*8;
  int colBase = blockIdx.y*128 + tx*8;
  #pragma unroll
  for(int i=0;i<8;i++){
    int r = rowBase + i;
    if(r < N_NODES){
      float s = scale[r];
      float4 v0 = make_float4(acc[i][0]*s,acc[i][1]*s,acc[i][2]*s,acc[i][3]*s);
      float4 v1 = make_float4(acc[i][4]*s,acc[i][5]*s,acc[i][6]*s,acc[i][7]*s);
      *(float4*)(out + (size_t)r*HD + colBase)     = v0;
      *(float4*)(out + (size_t)r*HD + colBase + 4) = v1;
    }
  }
}

// ---------- aggregation: out[v] = dinv[v] * sum_{r in in(v)} t[r] + bias ----------
// t already has dinv[r] folded in (GEMM epilogue). One wave per node; lane = 4 feats.
// Edge loop unrolled x8 with independent gathers -> MLP=8 per wave.
template<int RELU, int POOL>
__global__ __launch_bounds__(256) void k_agg(const float* __restrict__ t,
    const int* __restrict__ ptr, const int* __restrict__ src,
    const float* __restrict__ dinv, const float* __restrict__ bias,
    float* __restrict__ out, unsigned* __restrict__ gkeys,
    const int* __restrict__ batch){
  int v = blockIdx.x*4 + (threadIdx.x >> 6);
  if(v >= N_NODES) return;
  int f = (threadIdx.x & 63) * 4;
  float ax=0.f, ay=0.f, az=0.f, aw=0.f;
  int j0 = ptr[v], j1 = ptr[v+1];

  int j = j0;
  for(; j + 8 <= j1; j += 8){
    int idx[8];
    #pragma unroll
    for(int u=0;u<8;u++) idx[u] = src[j+u];
    float4 h[8];
    #pragma unroll
    for(int u=0;u<8;u++) h[u] = *(const float4*)(t + (size_t)idx[u]*HD + f);
    #pragma unroll
    for(int u=0;u<8;u++){
      ax += h[u].x; ay += h[u].y; az += h[u].z; aw += h[u].w;
    }
  }
  if(j < j1){
    // predicated tail group (inactive slots re-load src[j0]: L1 hit, weight 0)
    int idx[8]; float w[8];
    #pragma unroll
    for(int u=0;u<8;u++){
      int jj = j+u;
      bool act = jj < j1;
      idx[u] = act ? src[jj] : src[j0];
      w[u] = act ? 1.f : 0.f;
    }
    float4 h[8];
    #pragma unroll
    for(int u=0;u<8;u++) h[u] = *(const float4*)(t + (size_t)idx[u]*HD + f);
    #pragma unroll
    for(int u=0;u<8;u++){
      ax = fmaf(w[u], h[u].x, ax); ay = fmaf(w[u], h[u].y, ay);
      az = fmaf(w[u], h[u].z, az); aw = fmaf(w[u], h[u].w, aw);
    }
  }

  float dv = dinv[v];
  float4 b4 = *(const float4*)(bias + f);
  float4 acc;
  acc.x = fmaf(ax, dv, b4.x);
  acc.y = fmaf(ay, dv, b4.y);
  acc.z = fmaf(az, dv, b4.z);
  acc.w = fmaf(aw, dv, b4.w);
  if(RELU){
    acc.x = fmaxf(acc.x, 0.f); acc.y = fmaxf(acc.y, 0.f);
    acc.z = fmaxf(acc.z, 0.f); acc.w = fmaxf(acc.w, 0.f);
  }
  if(POOL){
    int g = batch[v];
    unsigned* gp = gkeys + (size_t)g*HD + f;
    atomicMax(gp+0, f2key(acc.x));
    atomicMax(gp+1, f2key(acc.y));
    atomicMax(gp+2, f2key(acc.z));
    atomicMax(gp+3, f2key(acc.w));
  } else {
    *(float4*)(out + (size_t)v*HD + f) = acc;
  }
}

// ---------- head: logits = g @ Wc + bc; log_softmax ----------
__global__ void k_head(const unsigned* __restrict__ gk, const float* __restrict__ Wc,
                       const float* __restrict__ bc, float* __restrict__ out){
  int i = threadIdx.x;
  if(i >= NG) return;
  float a0 = 0.f, a1 = 0.f;
  for(int k=0;k<HD;k++){
    float gv = key2f(gk[(size_t)i*HD + k]);
    a0 = fmaf(gv, Wc[2*k],   a0);
    a1 = fmaf(gv, Wc[2*k+1], a1);
  }
  a0 += bc[0]; a1 += bc[1];
  float m = fmaxf(a0, a1);
  float lse = m + logf(expf(a0-m) + expf(a1-m));
  out[2*i]   = a0 - lse;
  out[2*i+1] = a1 - lse;
}

extern "C" void kernel_launch(void* const* d_in, const int* in_sizes, int n_in,
                              void* d_out, int out_size, void* d_ws, size_t ws_size,
                              hipStream_t stream){
  (void)in_sizes; (void)n_in; (void)out_size; (void)ws_size;
  const float* x   = (const float*)d_in[0];
  const int*   ei  = (const int*)d_in[1];
  const int*   bat = (const int*)d_in[2];
  const float* W1  = (const float*)d_in[3];
  const float* b1  = (const float*)d_in[4];
  const float* W2  = (const float*)d_in[5];
  const float* b2  = (const float*)d_in[6];
  const float* Wc  = (const float*)d_in[7];
  const float* bc  = (const float*)d_in[8];
  float* out = (float*)d_out;

  char* ws = (char*)d_ws;
  size_t off = 0;
  auto alloc = [&](size_t bytes)->void*{
    void* p = ws + off; off = (off + bytes + 255) & ~(size_t)255; return p;
  };
  float*    T      = (float*)alloc((size_t)N_NODES*HD*4);
  float*    Hb     = (float*)alloc((size_t)N_NODES*HD*4);
  int*      deg    = (int*)alloc((size_t)N_NODES*4);
  float*    dinv   = (float*)alloc((size_t)N_NODES*4);
  int*      ptr    = (int*)alloc((size_t)(N_NODES+1)*4);
  int*      cursor = (int*)alloc((size_t)N_NODES*4);
  int*      src    = (int*)alloc((size_t)(N_EDGES+N_NODES)*4);
  int*      partials = (int*)alloc(512*4);
  unsigned* gkeys  = (unsigned*)alloc((size_t)NG*HD*4);

  const int M = N_EDGES + N_NODES;
  const int nbM = (M + 255)/256;
  const int nbN = (N_NODES + 255)/256;

  hipMemsetAsync(deg,   0, (size_t)N_NODES*4, stream);
  hipMemsetAsync(gkeys, 0, (size_t)NG*HD*4,   stream);

  k_deg  <<<nbM, 256, 0, stream>>>(ei, deg);
  k_scan1<<<nbN, 256, 0, stream>>>(deg, ptr, partials);
  k_scan2<<<1,   64,  0, stream>>>(partials, nbN, ptr + N_NODES);
  k_scan3<<<nbN, 256, 0, stream>>>(ptr, partials, cursor);
  k_fill <<<nbM, 256, 0, stream>>>(ei, cursor, src);
  k_dinv <<<nbN, 256, 0, stream>>>(deg, dinv);

  dim3 ggrid((N_NODES + 127)/128, HD/128);
  k_gemm<<<ggrid, 256, 0, stream>>>(x, W1, dinv, T);
  k_agg<1,0><<<(N_NODES+3)/4, 256, 0, stream>>>(T, ptr, src, dinv, b1, Hb, nullptr, nullptr);
  k_gemm<<<ggrid, 256, 0, stream>>>(Hb, W2, dinv, T);
  k_agg<0,1><<<(N_NODES+3)/4, 256, 0, stream>>>(T, ptr, src, dinv, b2, nullptr, gkeys, bat);
  k_head<<<1, 128, 0, stream>>>(gkeys, Wc, bc, out);
}

// Round 4
// 1235.171 us; speedup vs baseline: 1.0325x; 1.0257x over previous
//
#include <hip/hip_runtime.h>
#include <hip/hip_bf16.h>

#define N_NODES 100000
#define N_EDGES 800000
#define HD 256
#define NG 128

// ---------- order-preserving float <-> uint map (for atomicMax pooling) ----------
__device__ __forceinline__ unsigned f2key(float f){
  unsigned u = __float_as_uint(f);
  return (u & 0x80000000u) ? ~u : (u | 0x80000000u);
}
__device__ __forceinline__ float key2f(unsigned k){
  unsigned u = (k & 0x80000000u) ? (k & 0x7FFFFFFFu) : ~k;
  return __uint_as_float(u);
}

// ---------- bf16 helpers (manual, RNE) ----------
__device__ __forceinline__ unsigned short f2bf(float f){
  unsigned u = __float_as_uint(f);
  unsigned r = (u + 0x7FFFu + ((u >> 16) & 1u)) >> 16;
  return (unsigned short)r;
}
__device__ __forceinline__ float bf2f(unsigned short h){
  return __uint_as_float(((unsigned)h) << 16);
}

// ---------- CSR build ----------
__global__ void k_deg(const int* __restrict__ ei, int* __restrict__ deg){
  int e = blockIdx.x*256 + threadIdx.x;
  const int M = N_EDGES + N_NODES;
  if(e < M){
    int c = (e < N_EDGES) ? ei[N_EDGES + e] : (e - N_EDGES);
    atomicAdd(&deg[c], 1);
  }
}

__global__ void k_scan1(const int* __restrict__ deg, int* __restrict__ ptr,
                        int* __restrict__ partials){
  __shared__ int s[256];
  int tid = threadIdx.x;
  int i = blockIdx.x*256 + tid;
  int v = (i < N_NODES) ? deg[i] : 0;
  s[tid] = v; __syncthreads();
  for(int off=1; off<256; off<<=1){
    int t = (tid >= off) ? s[tid-off] : 0;
    __syncthreads();
    s[tid] += t;
    __syncthreads();
  }
  if(i < N_NODES) ptr[i] = s[tid] - v;     // exclusive within chunk
  if(tid == 255) partials[blockIdx.x] = s[255];
}

__global__ void k_scan2(int* __restrict__ partials, int nb, int* __restrict__ ptrN){
  if(threadIdx.x == 0 && blockIdx.x == 0){
    int run = 0;
    for(int b=0;b<nb;b++){ int t = partials[b]; partials[b] = run; run += t; }
    *ptrN = run;
  }
}

__global__ void k_scan3(int* __restrict__ ptr, const int* __restrict__ partials,
                        int* __restrict__ cursor){
  int i = blockIdx.x*256 + threadIdx.x;
  if(i < N_NODES){
    int v = ptr[i] + partials[blockIdx.x];
    ptr[i] = v; cursor[i] = v;
  }
}

__global__ void k_fill(const int* __restrict__ ei, int* __restrict__ cursor,
                       int* __restrict__ src){
  int e = blockIdx.x*256 + threadIdx.x;
  const int M = N_EDGES + N_NODES;
  if(e < M){
    int r, c;
    if(e < N_EDGES){ r = ei[e]; c = ei[N_EDGES + e]; }
    else           { r = c = e - N_EDGES; }
    int pos = atomicAdd(&cursor[c], 1);
    src[pos] = r;
  }
}

__global__ void k_dinv(const int* __restrict__ deg, float* __restrict__ dinv){
  int i = blockIdx.x*256 + threadIdx.x;
  if(i < N_NODES) dinv[i] = rsqrtf((float)deg[i]);   // deg >= 1 (self-loops)
}

// ---------- f32 GEMM: out_bf16[N,256] = (A[N,256] @ W[256,256]) * scale[row] ----------
__global__ __launch_bounds__(256) void k_gemm(const float* __restrict__ A,
                                              const float* __restrict__ W,
                                              const float* __restrict__ scale,
                                              unsigned short* __restrict__ out){
  __shared__ float As[16][132];   // [k][m], padded
  __shared__ float Bs[16][132];   // [k][n], padded
  int tid = threadIdx.x;
  int ty = tid >> 4, tx = tid & 15;
  float acc[8][8];
  #pragma unroll
  for(int i=0;i<8;i++)
    #pragma unroll
    for(int j=0;j<8;j++) acc[i][j] = 0.f;

  int ar = tid >> 1;            // 0..127
  int ac = (tid & 1) << 3;      // 0 or 8
  int grow = blockIdx.x*128 + ar;
  int brow = tid >> 4;          // 0..15
  int bcol = (tid & 15) << 3;   // 0..120
  const float* aptr = A + (size_t)grow*HD + ac;
  const float* bptr = W + (size_t)brow*HD + blockIdx.y*128 + bcol;
  bool aval = grow < N_NODES;

  for(int k0=0;k0<HD;k0+=16){
    float4 a0 = make_float4(0,0,0,0), a1 = a0;
    if(aval){ a0 = *(const float4*)(aptr); a1 = *(const float4*)(aptr+4); }
    float4 b0 = *(const float4*)(bptr);
    float4 b1 = *(const float4*)(bptr+4);
    aptr += 16; bptr += (size_t)16*HD;
    __syncthreads();
    As[ac+0][ar]=a0.x; As[ac+1][ar]=a0.y; As[ac+2][ar]=a0.z; As[ac+3][ar]=a0.w;
    As[ac+4][ar]=a1.x; As[ac+5][ar]=a1.y; As[ac+6][ar]=a1.z; As[ac+7][ar]=a1.w;
    *(float4*)&Bs[brow][bcol]   = b0;
    *(float4*)&Bs[brow][bcol+4] = b1;
    __syncthreads();
    #pragma unroll
    for(int kk=0;kk<16;kk++){
      float a[8], b[8];
      *(float4*)&a[0] = *(const float4*)&As[kk][ty*8];
      *(float4*)&a[4] = *(const float4*)&As[kk][ty*8+4];
      *(float4*)&b[0] = *(const float4*)&Bs[kk][tx*8];
      *(float4*)&b[4] = *(const float4*)&Bs[kk][tx*8+4];
      #pragma unroll
      for(int i=0;i<8;i++)
        #pragma unroll
        for(int j=0;j<8;j++) acc[i][j] = fmaf(a[i], b[j], acc[i][j]);
    }
  }
  int rowBase = blockIdx.x*128 + ty*8;
  int colBase = blockIdx.y*128 + tx*8;
  #pragma unroll
  for(int i=0;i<8;i++){
    int r = rowBase + i;
    if(r < N_NODES){
      float s = scale[r];
      ushort4 s0 = make_ushort4(f2bf(acc[i][0]*s), f2bf(acc[i][1]*s),
                                f2bf(acc[i][2]*s), f2bf(acc[i][3]*s));
      ushort4 s1 = make_ushort4(f2bf(acc[i][4]*s), f2bf(acc[i][5]*s),
                                f2bf(acc[i][6]*s), f2bf(acc[i][7]*s));
      *(ushort4*)(out + (size_t)r*HD + colBase)     = s0;
      *(ushort4*)(out + (size_t)r*HD + colBase + 4) = s1;
    }
  }
}

// ---------- aggregation: out[v] = dinv[v] * sum_{r in in(v)} t[r] + bias ----------
// t is bf16 with dinv[r] pre-folded. One wave per node; lane = 4 feats (8B).
// 8 gathers batched per iteration; launch_bounds(256,2) -> 128 VGPR so they stay in flight.
template<int RELU, int POOL>
__global__ __launch_bounds__(256, 2) void k_agg(const unsigned short* __restrict__ t,
    const int* __restrict__ ptr, const int* __restrict__ src,
    const float* __restrict__ dinv, const float* __restrict__ bias,
    float* __restrict__ out, unsigned* __restrict__ gkeys,
    const int* __restrict__ batch){
  int v = blockIdx.x*4 + (threadIdx.x >> 6);
  if(v >= N_NODES) return;
  int lane = threadIdx.x & 63;
  const unsigned short* tl = t + lane*4;
  float ax=0.f, ay=0.f, az=0.f, aw=0.f;
  int j0 = ptr[v], j1 = ptr[v+1];

  int j = j0;
  for(; j + 8 <= j1; j += 8){
    int idx[8];
    #pragma unroll
    for(int u=0;u<8;u++) idx[u] = src[j+u];
    ushort4 h[8];
    #pragma unroll
    for(int u=0;u<8;u++) h[u] = *(const ushort4*)(tl + (size_t)idx[u]*HD);
    #pragma unroll
    for(int u=0;u<8;u++){
      ax += bf2f(h[u].x); ay += bf2f(h[u].y);
      az += bf2f(h[u].z); aw += bf2f(h[u].w);
    }
  }
  if(j < j1){
    // predicated tail group (inactive slots re-load src[j0]: L1 hit, weight 0)
    int idx[8]; float w[8];
    int base = src[j0];
    #pragma unroll
    for(int u=0;u<8;u++){
      int jj = j+u;
      bool act = jj < j1;
      idx[u] = act ? src[jj] : base;
      w[u] = act ? 1.f : 0.f;
    }
    ushort4 h[8];
    #pragma unroll
    for(int u=0;u<8;u++) h[u] = *(const ushort4*)(tl + (size_t)idx[u]*HD);
    #pragma unroll
    for(int u=0;u<8;u++){
      ax = fmaf(w[u], bf2f(h[u].x), ax); ay = fmaf(w[u], bf2f(h[u].y), ay);
      az = fmaf(w[u], bf2f(h[u].z), az); aw = fmaf(w[u], bf2f(h[u].w), aw);
    }
  }

  float dv = dinv[v];
  int f = lane*4;
  float4 b4 = *(const float4*)(bias + f);
  float4 acc;
  acc.x = fmaf(ax, dv, b4.x);
  acc.y = fmaf(ay, dv, b4.y);
  acc.z = fmaf(az, dv, b4.z);
  acc.w = fmaf(aw, dv, b4.w);
  if(RELU){
    acc.x = fmaxf(acc.x, 0.f); acc.y = fmaxf(acc.y, 0.f);
    acc.z = fmaxf(acc.z, 0.f); acc.w = fmaxf(acc.w, 0.f);
  }
  if(POOL){
    int g = batch[v];
    unsigned* gp = gkeys + (size_t)g*HD + f;
    atomicMax(gp+0, f2key(acc.x));
    atomicMax(gp+1, f2key(acc.y));
    atomicMax(gp+2, f2key(acc.z));
    atomicMax(gp+3, f2key(acc.w));
  } else {
    *(float4*)(out + (size_t)v*HD + f) = acc;
  }
}

// ---------- head: logits = g @ Wc + bc; log_softmax ----------
__global__ void k_head(const unsigned* __restrict__ gk, const float* __restrict__ Wc,
                       const float* __restrict__ bc, float* __restrict__ out){
  int i = threadIdx.x;
  if(i >= NG) return;
  float a0 = 0.f, a1 = 0.f;
  for(int k=0;k<HD;k++){
    float gv = key2f(gk[(size_t)i*HD + k]);
    a0 = fmaf(gv, Wc[2*k],   a0);
    a1 = fmaf(gv, Wc[2*k+1], a1);
  }
  a0 += bc[0]; a1 += bc[1];
  float m = fmaxf(a0, a1);
  float lse = m + logf(expf(a0-m) + expf(a1-m));
  out[2*i]   = a0 - lse;
  out[2*i+1] = a1 - lse;
}

extern "C" void kernel_launch(void* const* d_in, const int* in_sizes, int n_in,
                              void* d_out, int out_size, void* d_ws, size_t ws_size,
                              hipStream_t stream){
  (void)in_sizes; (void)n_in; (void)out_size; (void)ws_size;
  const float* x   = (const float*)d_in[0];
  const int*   ei  = (const int*)d_in[1];
  const int*   bat = (const int*)d_in[2];
  const float* W1  = (const float*)d_in[3];
  const float* b1  = (const float*)d_in[4];
  const float* W2  = (const float*)d_in[5];
  const float* b2  = (const float*)d_in[6];
  const float* Wc  = (const float*)d_in[7];
  const float* bc  = (const float*)d_in[8];
  float* out = (float*)d_out;

  char* ws = (char*)d_ws;
  size_t off = 0;
  auto alloc = [&](size_t bytes)->void*{
    void* p = ws + off; off = (off + bytes + 255) & ~(size_t)255; return p;
  };
  unsigned short* T = (unsigned short*)alloc((size_t)N_NODES*HD*2);  // bf16 gathered matrix
  float*    Hb     = (float*)alloc((size_t)N_NODES*HD*4);
  int*      deg    = (int*)alloc((size_t)N_NODES*4);
  float*    dinv   = (float*)alloc((size_t)N_NODES*4);
  int*      ptr    = (int*)alloc((size_t)(N_NODES+1)*4);
  int*      cursor = (int*)alloc((size_t)N_NODES*4);
  int*      src    = (int*)alloc((size_t)(N_EDGES+N_NODES)*4);
  int*      partials = (int*)alloc(512*4);
  unsigned* gkeys  = (unsigned*)alloc((size_t)NG*HD*4);

  const int M = N_EDGES + N_NODES;
  const int nbM = (M + 255)/256;
  const int nbN = (N_NODES + 255)/256;

  hipMemsetAsync(deg,   0, (size_t)N_NODES*4, stream);
  hipMemsetAsync(gkeys, 0, (size_t)NG*HD*4,   stream);

  k_deg  <<<nbM, 256, 0, stream>>>(ei, deg);
  k_scan1<<<nbN, 256, 0, stream>>>(deg, ptr, partials);
  k_scan2<<<1,   64,  0, stream>>>(partials, nbN, ptr + N_NODES);
  k_scan3<<<nbN, 256, 0, stream>>>(ptr, partials, cursor);
  k_fill <<<nbM, 256, 0, stream>>>(ei, cursor, src);
  k_dinv <<<nbN, 256, 0, stream>>>(deg, dinv);

  dim3 ggrid((N_NODES + 127)/128, HD/128);
  k_gemm<<<ggrid, 256, 0, stream>>>(x, W1, dinv, T);
  k_agg<1,0><<<(N_NODES+3)/4, 256, 0, stream>>>(T, ptr, src, dinv, b1, Hb, nullptr, nullptr);
  k_gemm<<<ggrid, 256, 0, stream>>>(Hb, W2, dinv, T);
  k_agg<0,1><<<(N_NODES+3)/4, 256, 0, stream>>>(T, ptr, src, dinv, b2, nullptr, gkeys, bat);
  k_head<<<1, 128, 0, stream>>>(gkeys, Wc, bc, out);
}

// Round 6
// 1221.854 us; speedup vs baseline: 1.0438x; 1.0109x over previous
//
#include <hip/hip_runtime.h>
#include <hip/hip_bf16.h>

#define N_NODES 100000
#define N_EDGES 800000
#define HD 256
#define NG 128

// ---------- order-preserving float <-> uint map (for atomicMax pooling) ----------
__device__ __forceinline__ unsigned f2key(float f){
  unsigned u = __float_as_uint(f);
  return (u & 0x80000000u) ? ~u : (u | 0x80000000u);
}
__device__ __forceinline__ float key2f(unsigned k){
  unsigned u = (k & 0x80000000u) ? (k & 0x7FFFFFFFu) : ~k;
  return __uint_as_float(u);
}

// ---------- bf16 helpers (manual, RNE) ----------
__device__ __forceinline__ unsigned short f2bf(float f){
  unsigned u = __float_as_uint(f);
  unsigned r = (u + 0x7FFFu + ((u >> 16) & 1u)) >> 16;
  return (unsigned short)r;
}
// packed u32 of 2 bf16 -> two floats
__device__ __forceinline__ float bflo(unsigned u){ return __uint_as_float(u << 16); }
__device__ __forceinline__ float bfhi(unsigned u){ return __uint_as_float(u & 0xFFFF0000u); }

// ---------- CSR build ----------
__global__ void k_deg(const int* __restrict__ ei, int* __restrict__ deg){
  int e = blockIdx.x*256 + threadIdx.x;
  const int M = N_EDGES + N_NODES;
  if(e < M){
    int c = (e < N_EDGES) ? ei[N_EDGES + e] : (e - N_EDGES);
    atomicAdd(&deg[c], 1);
  }
}

__global__ void k_scan1(const int* __restrict__ deg, int* __restrict__ ptr,
                        int* __restrict__ partials){
  __shared__ int s[256];
  int tid = threadIdx.x;
  int i = blockIdx.x*256 + tid;
  int v = (i < N_NODES) ? deg[i] : 0;
  s[tid] = v; __syncthreads();
  for(int off=1; off<256; off<<=1){
    int t = (tid >= off) ? s[tid-off] : 0;
    __syncthreads();
    s[tid] += t;
    __syncthreads();
  }
  if(i < N_NODES) ptr[i] = s[tid] - v;     // exclusive within chunk
  if(tid == 255) partials[blockIdx.x] = s[255];
}

__global__ void k_scan2(int* __restrict__ partials, int nb, int* __restrict__ ptrN){
  if(threadIdx.x == 0 && blockIdx.x == 0){
    int run = 0;
    for(int b=0;b<nb;b++){ int t = partials[b]; partials[b] = run; run += t; }
    *ptrN = run;
  }
}

__global__ void k_scan3(int* __restrict__ ptr, const int* __restrict__ partials,
                        int* __restrict__ cursor){
  int i = blockIdx.x*256 + threadIdx.x;
  if(i < N_NODES){
    int v = ptr[i] + partials[blockIdx.x];
    ptr[i] = v; cursor[i] = v;
  }
}

__global__ void k_fill(const int* __restrict__ ei, int* __restrict__ cursor,
                       int* __restrict__ src){
  int e = blockIdx.x*256 + threadIdx.x;
  const int M = N_EDGES + N_NODES;
  if(e < M){
    int r, c;
    if(e < N_EDGES){ r = ei[e]; c = ei[N_EDGES + e]; }
    else           { r = c = e - N_EDGES; }
    int pos = atomicAdd(&cursor[c], 1);
    src[pos] = r;
  }
}

__global__ void k_dinv(const int* __restrict__ deg, float* __restrict__ dinv){
  int i = blockIdx.x*256 + threadIdx.x;
  if(i < N_NODES) dinv[i] = rsqrtf((float)deg[i]);   // deg >= 1 (self-loops)
}

// ---------- f32 GEMM: out_bf16[N,256] = (A[N,256] @ W[256,256]) * scale[row] ----------
__global__ __launch_bounds__(256) void k_gemm(const float* __restrict__ A,
                                              const float* __restrict__ W,
                                              const float* __restrict__ scale,
                                              unsigned short* __restrict__ out){
  __shared__ float As[16][132];   // [k][m], padded
  __shared__ float Bs[16][132];   // [k][n], padded
  int tid = threadIdx.x;
  int ty = tid >> 4, tx = tid & 15;
  float acc[8][8];
  #pragma unroll
  for(int i=0;i<8;i++)
    #pragma unroll
    for(int j=0;j<8;j++) acc[i][j] = 0.f;

  int ar = tid >> 1;            // 0..127
  int ac = (tid & 1) << 3;      // 0 or 8
  int grow = blockIdx.x*128 + ar;
  int brow = tid >> 4;          // 0..15
  int bcol = (tid & 15) << 3;   // 0..120
  const float* aptr = A + (size_t)grow*HD + ac;
  const float* bptr = W + (size_t)brow*HD + blockIdx.y*128 + bcol;
  bool aval = grow < N_NODES;

  for(int k0=0;k0<HD;k0+=16){
    float4 a0 = make_float4(0,0,0,0), a1 = a0;
    if(aval){ a0 = *(const float4*)(aptr); a1 = *(const float4*)(aptr+4); }
    float4 b0 = *(const float4*)(bptr);
    float4 b1 = *(const float4*)(bptr+4);
    aptr += 16; bptr += (size_t)16*HD;
    __syncthreads();
    As[ac+0][ar]=a0.x; As[ac+1][ar]=a0.y; As[ac+2][ar]=a0.z; As[ac+3][ar]=a0.w;
    As[ac+4][ar]=a1.x; As[ac+5][ar]=a1.y; As[ac+6][ar]=a1.z; As[ac+7][ar]=a1.w;
    *(float4*)&Bs[brow][bcol]   = b0;
    *(float4*)&Bs[brow][bcol+4] = b1;
    __syncthreads();
    #pragma unroll
    for(int kk=0;kk<16;kk++){
      float a[8], b[8];
      *(float4*)&a[0] = *(const float4*)&As[kk][ty*8];
      *(float4*)&a[4] = *(const float4*)&As[kk][ty*8+4];
      *(float4*)&b[0] = *(const float4*)&Bs[kk][tx*8];
      *(float4*)&b[4] = *(const float4*)&Bs[kk][tx*8+4];
      #pragma unroll
      for(int i=0;i<8;i++)
        #pragma unroll
        for(int j=0;j<8;j++) acc[i][j] = fmaf(a[i], b[j], acc[i][j]);
    }
  }
  int rowBase = blockIdx.x*128 + ty*8;
  int colBase = blockIdx.y*128 + tx*8;
  #pragma unroll
  for(int i=0;i<8;i++){
    int r = rowBase + i;
    if(r < N_NODES){
      float s = scale[r];
      ushort4 s0 = make_ushort4(f2bf(acc[i][0]*s), f2bf(acc[i][1]*s),
                                f2bf(acc[i][2]*s), f2bf(acc[i][3]*s));
      ushort4 s1 = make_ushort4(f2bf(acc[i][4]*s), f2bf(acc[i][5]*s),
                                f2bf(acc[i][6]*s), f2bf(acc[i][7]*s));
      *(ushort4*)(out + (size_t)r*HD + colBase)     = s0;
      *(ushort4*)(out + (size_t)r*HD + colBase + 4) = s1;
    }
  }
}

// ---------- aggregation: out[v] = dinv[v] * sum_{r in in(v)} t[r] + bias ----------
// t is bf16 with dinv[r] pre-folded. One wave per node; lane = 4 feats (8B).
// Gathers forced in-flight 8-deep via inline-asm global_load + single s_waitcnt.
template<int RELU, int POOL>
__global__ __launch_bounds__(256) void k_agg(const unsigned short* __restrict__ t,
    const int* __restrict__ ptr, const int* __restrict__ src,
    const float* __restrict__ dinv, const float* __restrict__ bias,
    float* __restrict__ out, unsigned* __restrict__ gkeys,
    const int* __restrict__ batch){
  int v = blockIdx.x*4 + (threadIdx.x >> 6);
  if(v >= N_NODES) return;
  const int lane = threadIdx.x & 63;
  const unsigned short* tl = t + lane*4;

  int j0 = ptr[v], j1 = ptr[v+1];
  float dv = dinv[v];                          // issued early, overlaps gathers
  int f = lane*4;
  float4 b4 = *(const float4*)(bias + f);
  int gidx = 0;
  if(POOL) gidx = batch[v];

  float ax=0.f, ay=0.f, az=0.f, aw=0.f;
  const int last = j1 - 1;                     // deg >= 1 always (self-loop)

  for(int j=j0; j<j1; j+=8){
    // clamped indices + weights (weight-0 slots reuse a real row, stay in batch)
    int jc1=j+1>last?last:j+1, jc2=j+2>last?last:j+2, jc3=j+3>last?last:j+3;
    int jc4=j+4>last?last:j+4, jc5=j+5>last?last:j+5, jc6=j+6>last?last:j+6;
    int jc7=j+7>last?last:j+7;
    int i0=src[j],   i1=src[jc1], i2=src[jc2], i3=src[jc3];
    int i4=src[jc4], i5=src[jc5], i6=src[jc6], i7=src[jc7];
    float w1=(j+1<j1)?1.f:0.f, w2=(j+2<j1)?1.f:0.f, w3=(j+3<j1)?1.f:0.f;
    float w4=(j+4<j1)?1.f:0.f, w5=(j+5<j1)?1.f:0.f, w6=(j+6<j1)?1.f:0.f;
    float w7=(j+7<j1)?1.f:0.f;

    const unsigned short* p0 = tl + (size_t)i0*HD;
    const unsigned short* p1 = tl + (size_t)i1*HD;
    const unsigned short* p2 = tl + (size_t)i2*HD;
    const unsigned short* p3 = tl + (size_t)i3*HD;
    const unsigned short* p4 = tl + (size_t)i4*HD;
    const unsigned short* p5 = tl + (size_t)i5*HD;
    const unsigned short* p6 = tl + (size_t)i6*HD;
    const unsigned short* p7 = tl + (size_t)i7*HD;

    uint2 d0,d1,d2,d3,d4,d5,d6,d7;
    asm volatile("global_load_dwordx2 %0, %1, off" : "=v"(d0) : "v"(p0));
    asm volatile("global_load_dwordx2 %0, %1, off" : "=v"(d1) : "v"(p1));
    asm volatile("global_load_dwordx2 %0, %1, off" : "=v"(d2) : "v"(p2));
    asm volatile("global_load_dwordx2 %0, %1, off" : "=v"(d3) : "v"(p3));
    asm volatile("global_load_dwordx2 %0, %1, off" : "=v"(d4) : "v"(p4));
    asm volatile("global_load_dwordx2 %0, %1, off" : "=v"(d5) : "v"(p5));
    asm volatile("global_load_dwordx2 %0, %1, off" : "=v"(d6) : "v"(p6));
    asm volatile("global_load_dwordx2 %0, %1, off" : "=v"(d7) : "v"(p7));
    asm volatile("s_waitcnt vmcnt(0)" ::: "memory");
    __builtin_amdgcn_sched_barrier(0);

    ax += bflo(d0.x); ay += bfhi(d0.x); az += bflo(d0.y); aw += bfhi(d0.y);
    ax = fmaf(w1, bflo(d1.x), ax); ay = fmaf(w1, bfhi(d1.x), ay);
    az = fmaf(w1, bflo(d1.y), az); aw = fmaf(w1, bfhi(d1.y), aw);
    ax = fmaf(w2, bflo(d2.x), ax); ay = fmaf(w2, bfhi(d2.x), ay);
    az = fmaf(w2, bflo(d2.y), az); aw = fmaf(w2, bfhi(d2.y), aw);
    ax = fmaf(w3, bflo(d3.x), ax); ay = fmaf(w3, bfhi(d3.x), ay);
    az = fmaf(w3, bflo(d3.y), az); aw = fmaf(w3, bfhi(d3.y), aw);
    ax = fmaf(w4, bflo(d4.x), ax); ay = fmaf(w4, bfhi(d4.x), ay);
    az = fmaf(w4, bflo(d4.y), az); aw = fmaf(w4, bfhi(d4.y), aw);
    ax = fmaf(w5, bflo(d5.x), ax); ay = fmaf(w5, bfhi(d5.x), ay);
    az = fmaf(w5, bflo(d5.y), az); aw = fmaf(w5, bfhi(d5.y), aw);
    ax = fmaf(w6, bflo(d6.x), ax); ay = fmaf(w6, bfhi(d6.x), ay);
    az = fmaf(w6, bflo(d6.y), az); aw = fmaf(w6, bfhi(d6.y), aw);
    ax = fmaf(w7, bflo(d7.x), ax); ay = fmaf(w7, bfhi(d7.x), ay);
    az = fmaf(w7, bflo(d7.y), az); aw = fmaf(w7, bfhi(d7.y), aw);
  }

  float4 acc;
  acc.x = fmaf(ax, dv, b4.x);
  acc.y = fmaf(ay, dv, b4.y);
  acc.z = fmaf(az, dv, b4.z);
  acc.w = fmaf(aw, dv, b4.w);
  if(RELU){
    acc.x = fmaxf(acc.x, 0.f); acc.y = fmaxf(acc.y, 0.f);
    acc.z = fmaxf(acc.z, 0.f); acc.w = fmaxf(acc.w, 0.f);
  }
  if(POOL){
    unsigned* gp = gkeys + (size_t)gidx*HD + f;
    atomicMax(gp+0, f2key(acc.x));
    atomicMax(gp+1, f2key(acc.y));
    atomicMax(gp+2, f2key(acc.z));
    atomicMax(gp+3, f2key(acc.w));
  } else {
    *(float4*)(out + (size_t)v*HD + f) = acc;
  }
}

// ---------- head: logits = g @ Wc + bc; log_softmax ----------
__global__ void k_head(const unsigned* __restrict__ gk, const float* __restrict__ Wc,
                       const float* __restrict__ bc, float* __restrict__ out){
  int i = threadIdx.x;
  if(i >= NG) return;
  float a0 = 0.f, a1 = 0.f;
  for(int k=0;k<HD;k++){
    float gv = key2f(gk[(size_t)i*HD + k]);
    a0 = fmaf(gv, Wc[2*k],   a0);
    a1 = fmaf(gv, Wc[2*k+1], a1);
  }
  a0 += bc[0]; a1 += bc[1];
  float m = fmaxf(a0, a1);
  float lse = m + logf(expf(a0-m) + expf(a1-m));
  out[2*i]   = a0 - lse;
  out[2*i+1] = a1 - lse;
}

extern "C" void kernel_launch(void* const* d_in, const int* in_sizes, int n_in,
                              void* d_out, int out_size, void* d_ws, size_t ws_size,
                              hipStream_t stream){
  (void)in_sizes; (void)n_in; (void)out_size; (void)ws_size;
  const float* x   = (const float*)d_in[0];
  const int*   ei  = (const int*)d_in[1];
  const int*   bat = (const int*)d_in[2];
  const float* W1  = (const float*)d_in[3];
  const float* b1  = (const float*)d_in[4];
  const float* W2  = (const float*)d_in[5];
  const float* b2  = (const float*)d_in[6];
  const float* Wc  = (const float*)d_in[7];
  const float* bc  = (const float*)d_in[8];
  float* out = (float*)d_out;

  char* ws = (char*)d_ws;
  size_t off = 0;
  auto alloc = [&](size_t bytes)->void*{
    void* p = ws + off; off = (off + bytes + 255) & ~(size_t)255; return p;
  };
  unsigned short* T = (unsigned short*)alloc((size_t)N_NODES*HD*2);  // bf16 gathered matrix
  float*    Hb     = (float*)alloc((size_t)N_NODES*HD*4);
  int*      deg    = (int*)alloc((size_t)N_NODES*4);
  float*    dinv   = (float*)alloc((size_t)N_NODES*4);
  int*      ptr    = (int*)alloc((size_t)(N_NODES+1)*4);
  int*      cursor = (int*)alloc((size_t)N_NODES*4);
  int*      src    = (int*)alloc((size_t)(N_EDGES+N_NODES)*4);
  int*      partials = (int*)alloc(512*4);
  unsigned* gkeys  = (unsigned*)alloc((size_t)NG*HD*4);

  const int M = N_EDGES + N_NODES;
  const int nbM = (M + 255)/256;
  const int nbN = (N_NODES + 255)/256;

  hipMemsetAsync(deg,   0, (size_t)N_NODES*4, stream);
  hipMemsetAsync(gkeys, 0, (size_t)NG*HD*4,   stream);

  k_deg  <<<nbM, 256, 0, stream>>>(ei, deg);
  k_scan1<<<nbN, 256, 0, stream>>>(deg, ptr, partials);
  k_scan2<<<1,   64,  0, stream>>>(partials, nbN, ptr + N_NODES);
  k_scan3<<<nbN, 256, 0, stream>>>(ptr, partials, cursor);
  k_fill <<<nbM, 256, 0, stream>>>(ei, cursor, src);
  k_dinv <<<nbN, 256, 0, stream>>>(deg, dinv);

  dim3 ggrid((N_NODES + 127)/128, HD/128);
  k_gemm<<<ggrid, 256, 0, stream>>>(x, W1, dinv, T);
  k_agg<1,0><<<(N_NODES+3)/4, 256, 0, stream>>>(T, ptr, src, dinv, b1, Hb, nullptr, nullptr);
  k_gemm<<<ggrid, 256, 0, stream>>>(Hb, W2, dinv, T);
  k_agg<0,1><<<(N_NODES+3)/4, 256, 0, stream>>>(T, ptr, src, dinv, b2, nullptr, gkeys, bat);
  k_head<<<1, 128, 0, stream>>>(gkeys, Wc, bc, out);
}